// Round 10
// baseline (426.789 us; speedup 1.0000x reference)
//
#include <hip/hip_runtime.h>

// CT parallel-beam pixel-driven back-projection. Static geometry.
// Fusions:
//  1) Opposing views (v, v+360) share fr (u' = 735-u): pre-summed at staging,
//     S[i] = row_v[i] + row_{v+360}[735-i] (fp32 add, one fp16 round).
//  2) View quad {v, v+180, v+360, v+540} x pixel ROTATION orbit: with
//     g1 = px*c + py*s, g2 = py*c - px*s, the 16 contributions are 4 visits
//     u = C+-g1, C+-g2; each serves pairA (v,v+360) for pixel q and pairB
//     (v+180,v+540) for the next orbit pixel.
//  3) LDS entry M[i] = (DA,SA,DB,SB) fp16 (8 B), D = S[i+1]-S[i]:
//     one ds_read_b64 + wv=pkrtz(fr,1) + two v_dot2_f32_f16 do both pairs'
//     2-tap interp: S + fr*D. No neighbor read, no 1-fr sub.
//  4) Two groups staged per barrier (90 barriers total).
#define BATCH 8
#define NVIEW 720
#define NPAIR 360
#define NGRP  180
#define NDET  736
#define IMGH  512
#define IMGW  512

#define DANG_F  ((float)(6.283185307179586 / 720.0))
#define RATIO_F ((float)(0.006641 / 0.0066))
#define UCENTER ((float)((NDET - 1) * 0.5))

typedef float  v2f __attribute__((ext_vector_type(2)));
typedef __fp16 v2h __attribute__((ext_vector_type(2)));
typedef __fp16 v4h __attribute__((ext_vector_type(4)));

struct Stage {
    float4 fa, ra, fb, rb;
    float  fa1, ra1, fb1, rb1;
};

// Staging: threads 0..367; sub = t>=184 selects group g+sub; thread owns
// bins i..i+3 of BOTH pairA (views v, v+360) and pairB (v+180, v+540).
// Overshoot scalars (fwd[i+4] at i=732 -> next row elem 0; rev[-1] -> prev
// row last elem) stay inside proj (fwd rows <= 361, rev rows >= 360) and
// land only in M[735], which is never read (i0 <= 731).
__device__ __forceinline__ void load_rows(const float* __restrict__ sino,
                                          int g, int t, Stage& S) {
    if (t < 368) {
        const int sub = (t >= 184);
        const int i   = 4 * (t - 184 * sub);
        const int v   = g + sub;
        const float* __restrict__ fA = sino + v * NDET;
        const float* __restrict__ rA = sino + (v + NPAIR) * NDET;
        const float* __restrict__ fB = sino + (v + 180) * NDET;
        const float* __restrict__ rB = sino + (v + 540) * NDET;
        S.fa = *(const float4*)(fA + i);         S.fa1 = fA[i + 4];
        S.ra = *(const float4*)(rA + (732 - i)); S.ra1 = rA[731 - i];
        S.fb = *(const float4*)(fB + i);         S.fb1 = fB[i + 4];
        S.rb = *(const float4*)(rB + (732 - i)); S.rb1 = rB[731 - i];
    }
}

__device__ __forceinline__ void write_rows(v4h* __restrict__ L,  // [2*NDET]
                                           int t, const Stage& S) {
    if (t < 368) {
        const int sub = (t >= 184);
        const int i   = 4 * (t - 184 * sub);
        const float sa0 = S.fa.x + S.ra.w, sa1 = S.fa.y + S.ra.z;
        const float sa2 = S.fa.z + S.ra.y, sa3 = S.fa.w + S.ra.x;
        const float sa4 = S.fa1 + S.ra1;
        const float sb0 = S.fb.x + S.rb.w, sb1 = S.fb.y + S.rb.z;
        const float sb2 = S.fb.z + S.rb.y, sb3 = S.fb.w + S.rb.x;
        const float sb4 = S.fb1 + S.rb1;
        // M[i+k] = (DA, SA, DB, SB)
        const v2h a0 = __builtin_amdgcn_cvt_pkrtz(sa1 - sa0, sa0);
        const v2h a1 = __builtin_amdgcn_cvt_pkrtz(sa2 - sa1, sa1);
        const v2h a2 = __builtin_amdgcn_cvt_pkrtz(sa3 - sa2, sa2);
        const v2h a3 = __builtin_amdgcn_cvt_pkrtz(sa4 - sa3, sa3);
        const v2h b0 = __builtin_amdgcn_cvt_pkrtz(sb1 - sb0, sb0);
        const v2h b1 = __builtin_amdgcn_cvt_pkrtz(sb2 - sb1, sb1);
        const v2h b2 = __builtin_amdgcn_cvt_pkrtz(sb3 - sb2, sb2);
        const v2h b3 = __builtin_amdgcn_cvt_pkrtz(sb4 - sb3, sb3);
        struct alignas(16) HOct { v4h a, b; };
        HOct o0 = { __builtin_shufflevector(a0, b0, 0, 1, 2, 3),
                    __builtin_shufflevector(a1, b1, 0, 1, 2, 3) };
        HOct o1 = { __builtin_shufflevector(a2, b2, 0, 1, 2, 3),
                    __builtin_shufflevector(a3, b3, 0, 1, 2, 3) };
        HOct* dst = (HOct*)(L + sub * NDET + i);
        dst[0] = o0;   // ds_write_b128
        dst[1] = o1;   // ds_write_b128
    }
}

// One u value: 2-view interp from pairA into accA and pairB into accB.
// 6 VALU + 1 ds_read_b64 serving 4 pixel-view contributions.
__device__ __forceinline__ void visit(const v4h* __restrict__ L,
                                      float u, float& accA, float& accB) {
    const int   i0 = (int)u;                      // u in [3.9, 731.1] always
    const float fr = __builtin_amdgcn_fractf(u);
    const v2h wv = __builtin_amdgcn_cvt_pkrtz(fr, 1.0f);
    const v4h M  = L[i0];                          // ds_read_b64
    const v2h A  = __builtin_shufflevector(M, M, 0, 1);  // (DA, SA)
    const v2h B  = __builtin_shufflevector(M, M, 2, 3);  // (DB, SB)
    accA = __builtin_amdgcn_fdot2(A, wv, accA, false);   // SA + fr*DA
    accB = __builtin_amdgcn_fdot2(B, wv, accB, false);
}

// 512 threads = 8 waves; wave = one h row of the top-left quadrant, lanes =
// 64 consecutive w. Thread owns the rotation orbit {(h,w), (511-w,h),
// (511-h,511-w), (w,511-h)}. Grid 1024 = exactly 4 blocks/CU. Bounds check
// proven unnecessary: |g1|,|g2| <= 255.5*sqrt2*1.00621 = 363.6 < 367.5 ->
// u in [3.9, 731.1], i0 <= 731.
__global__ __launch_bounds__(512, 8) void backproject_kernel(
    const float* __restrict__ proj,  // [B, V, D]
    float* __restrict__ out)         // [B, H, W]
{
    __shared__ alignas(16) v4h lds[2][2 * NDET];  // [dbuf][group g | g+1]
    __shared__ v2f cs[NGRP];

    const int tid = threadIdx.x;

    if (tid < NGRP) {
        float s, c;
        sincosf((float)tid * DANG_F, &s, &c);
        cs[tid] = (v2f){c * RATIO_F, s * RATIO_F};
    }

    const int b    = blockIdx.z;
    const int lane = tid & 63;
    const int h    = (int)blockIdx.y * 8 + (tid >> 6);   // [0, 256)
    const int w0   = (int)blockIdx.x * 64 + lane;        // [0, 256)

    const float px = (float)w0 - (float)(IMGW - 1) * 0.5f;
    const float py = (float)(IMGH - 1) * 0.5f - (float)h;

    const float* __restrict__ sino = proj + (size_t)b * NVIEW * NDET;

    // Orbit accumulators: q0=(h,w0), q1=(511-w0,h), q2=(511-h,511-w0),
    // q3=(w0,511-h)   (q_{k+1} = rotate q_k by +90deg).
    float acc0 = 0.f, acc1 = 0.f, acc2 = 0.f, acc3 = 0.f;

    Stage S = {};
    load_rows(sino, 0, tid, S);
    write_rows(lds[0], tid, S);
    load_rows(sino, 2, tid, S);
    __syncthreads();

    for (int g = 0; g < NGRP; g += 2) {
        const int buf = (g >> 1) & 1;
        const v4h* __restrict__ L = lds[buf];
#pragma unroll
        for (int sub = 0; sub < 2; ++sub) {
            const v2f t = cs[g + sub];
            // (g1, g2) = px*(c, -s) + py*(s, c)  -- packed fp32
            const v2f m1 = {t.x, -t.y};
            const v2f m2 = {t.y, t.x};
            const v2f pxv = {px, px};
            const v2f pyv = {py, py};
            const v2f gg = __builtin_elementwise_fma(pxv, m1, pyv * m2);
            const v2f cc = {UCENTER, UCENTER};
            const v2f up = cc + gg;   // (C+g1, C+g2)
            const v2f um = cc - gg;   // (C-g1, C-g2)
            const v4h* __restrict__ Ls = L + sub * NDET;

            visit(Ls, up.x, acc0, acc1);   // +g1: A->q0, B->q1
            visit(Ls, um.x, acc2, acc3);   // -g1: A->q2, B->q3
            visit(Ls, up.y, acc3, acc0);   // +g2: A->q3, B->q0
            visit(Ls, um.y, acc1, acc2);   // -g2: A->q1, B->q2
        }

        if (g < NGRP - 2) {
            // lds[buf^1] last read in the previous iteration, sealed by its
            // barrier -> safe to overwrite now.
            write_rows(lds[buf ^ 1], tid, S);
            if (g < NGRP - 4) load_rows(sino, g + 4, tid, S);
            __syncthreads();
        }
    }

    float* __restrict__ o = out + (size_t)b * IMGH * IMGW;
    const int hm = (IMGH - 1) - h;
    const int wm = (IMGW - 1) - w0;
    o[h  * IMGW + w0] = acc0 * DANG_F;   // q0, coalesced
    o[wm * IMGW + h ] = acc1 * DANG_F;   // q1, scattered (once)
    o[hm * IMGW + wm] = acc2 * DANG_F;   // q2, coalesced
    o[w0 * IMGW + hm] = acc3 * DANG_F;   // q3, scattered (once)
}

extern "C" void kernel_launch(void* const* d_in, const int* in_sizes, int n_in,
                              void* d_out, int out_size, void* d_ws, size_t ws_size,
                              hipStream_t stream) {
    const float* proj = (const float*)d_in[0];
    float* out = (float*)d_out;

    dim3 block(512, 1, 1);
    dim3 grid(4, 32, BATCH);   // 1024 blocks = exactly 4/CU, fully resident
    backproject_kernel<<<grid, block, 0, stream>>>(proj, out);
}

// Round 11
// 249.514 us; speedup vs baseline: 1.7105x; 1.7105x over previous
//
#include <hip/hip_runtime.h>

// CT parallel-beam pixel-driven back-projection. Static geometry.
// Fusions:
//  1) Opposing views (v, v+360) share fr (u' = 735-u): pre-summed at staging,
//     S[i] = row_v[i] + row_{v+360}[735-i] (fp32 add, one fp16 round).
//  2) View quad {v, v+180, v+360, v+540} x pixel ROTATION orbit: with
//     g1 = px*c + py*s, g2 = py*c - px*s, the 16 contributions are 4 visits
//     u = C+-g1, C+-g2; each serves pairA (v,v+360) for pixel q and pairB
//     (v+180,v+540) for the next orbit pixel.
//  3) Difference layout, 4 B entries (1-bank stride -> conflict-free):
//     entry = (D,S) fp16 with D = S[i+1]-S[i]; interp = fdot2((D,S),(fr,1)).
//  4) A/B block-interleave at 64-entry granularity: A bin i at entry
//     j = i + (i & ~63), B at j + 64 (+256 B) -> both pair reads merge into
//     ONE ds_read2_b32 offset0:0 offset1:64.
// R9 lessons baked in: NO multi-group register prefetch (spilled to scratch,
// 277 MB WRITE_SIZE), entry stride must stay 4 B (8 B entries -> 4-way bank
// conflicts).
#define BATCH 8
#define NVIEW 720
#define NPAIR 360
#define NGRP  180
#define NDET  736
#define IMGH  512
#define IMGW  512

#define DANG_F  ((float)(6.283185307179586 / 720.0))
#define RATIO_F ((float)(0.006641 / 0.0066))
#define UCENTER ((float)((NDET - 1) * 0.5))

// Entries per group-buffer: bin 735 -> j = 735 + 704 = 1439; B at +64 -> 1503.
#define LSTRIDE 1504

typedef float  v2f __attribute__((ext_vector_type(2)));
typedef __fp16 v2h __attribute__((ext_vector_type(2)));

// Staging (R8 structure, no spill): threads 0..183 build pairA sums (views
// g, g+360), 184..367 pairB (g+180, g+540). Thread owns bins i..i+3, needs
// S[i..i+4]: float4 + 1 scalar from each of fwd/rev rows. Overshoot scalars
// (fwd[i+4] at i=732; rev[-1]) stay inside proj (fwd rows <= 539, rev rows
// >= 360) and land only in bin 735's D, never read (i0 <= 731).
__device__ __forceinline__ void load_rows(const float* __restrict__ sino,
                                          int g, int t,
                                          float4& f4, float& f1,
                                          float4& r4, float& r1) {
    if (t < 368) {
        const int p  = (t >= 184);
        const int i  = 4 * (t - 184 * p);
        const int vf = g + 180 * p;
        const float* __restrict__ fwd = sino + vf * NDET;
        const float* __restrict__ rev = sino + (vf + NPAIR) * NDET;
        f4 = *(const float4*)(fwd + i);
        f1 = fwd[i + 4];
        r4 = *(const float4*)(rev + (732 - i));  // S-rev taps i..i+3 = (w,z,y,x)
        r1 = rev[731 - i];                       // tap i+4
    }
}

__device__ __forceinline__ void write_rows(v2h* __restrict__ L,  // [LSTRIDE]
                                           int t, float4 f4, float f1,
                                           float4 r4, float r1) {
    if (t < 368) {
        const int p = (t >= 184);
        const int i = 4 * (t - 184 * p);
        const float s0 = f4.x + r4.w;
        const float s1 = f4.y + r4.z;
        const float s2 = f4.z + r4.y;
        const float s3 = f4.w + r4.x;
        const float s4 = f1 + r1;
        // entry = (D, S); fdot2 weight = (fr, 1)
        const v2h n0 = __builtin_amdgcn_cvt_pkrtz(s1 - s0, s0);
        const v2h n1 = __builtin_amdgcn_cvt_pkrtz(s2 - s1, s1);
        const v2h n2 = __builtin_amdgcn_cvt_pkrtz(s3 - s2, s2);
        const v2h n3 = __builtin_amdgcn_cvt_pkrtz(s4 - s3, s3);
        // Block-interleaved index; i%64 in {0..60} so 4 entries never cross
        // a 64-block boundary -> contiguous, 16 B aligned.
        const int j0 = i + (i & ~63) + 64 * p;
        struct alignas(16) H4 { v2h a, b, c, d; };
        *(H4*)(L + j0) = H4{n0, n1, n2, n3};     // one ds_write_b128
    }
}

// One u value: 2-view interp from pairA into accA and pairB into accB.
// cvt, fract, pkrtz, and, add + one ds_read2_b32 + two v_dot2_f32_f16
// serving 4 pixel-view contributions.
__device__ __forceinline__ void visit(const v2h* __restrict__ L,
                                      float u, float& accA, float& accB) {
    const int   i0 = (int)u;                      // u in [3.9, 731.1] always
    const float fr = __builtin_amdgcn_fractf(u);
    const v2h wv = __builtin_amdgcn_cvt_pkrtz(fr, 1.0f);
    const int  j  = i0 + (i0 & ~63);
    const v2h A = L[j];            // } one ds_read2_b32 offset0:0 offset1:64
    const v2h B = L[j + 64];       // }
    accA = __builtin_amdgcn_fdot2(A, wv, accA, false);   // S + fr*D
    accB = __builtin_amdgcn_fdot2(B, wv, accB, false);
}

// 512 threads = 8 waves; wave = one h row of the top-left quadrant, lanes =
// 64 consecutive w. Thread owns the rotation orbit {(h,w), (511-w,h),
// (511-h,511-w), (w,511-h)}. Grid 1024 = exactly 4 blocks/CU. Bounds check
// proven unnecessary: |g1|,|g2| <= 255.5*sqrt2*1.00621 = 363.6 < 367.5 ->
// u in [3.9, 731.1], i0 <= 731.
__global__ __launch_bounds__(512, 8) void backproject_kernel(
    const float* __restrict__ proj,  // [B, V, D]
    float* __restrict__ out)         // [B, H, W]
{
    __shared__ alignas(16) v2h lds[2][LSTRIDE];
    __shared__ v2f cs[NGRP];

    const int tid = threadIdx.x;

    if (tid < NGRP) {
        float s, c;
        sincosf((float)tid * DANG_F, &s, &c);
        cs[tid] = (v2f){c * RATIO_F, s * RATIO_F};
    }

    const int b    = blockIdx.z;
    const int lane = tid & 63;
    const int h    = (int)blockIdx.y * 8 + (tid >> 6);   // [0, 256)
    const int w0   = (int)blockIdx.x * 64 + lane;        // [0, 256)

    const float px = (float)w0 - (float)(IMGW - 1) * 0.5f;
    const float py = (float)(IMGH - 1) * 0.5f - (float)h;

    const float* __restrict__ sino = proj + (size_t)b * NVIEW * NDET;

    // Orbit accumulators: q0=(h,w0), q1=(511-w0,h), q2=(511-h,511-w0),
    // q3=(w0,511-h)   (q_{k+1} = rotate q_k by +90deg).
    float acc0 = 0.f, acc1 = 0.f, acc2 = 0.f, acc3 = 0.f;

    float4 f4 = {0, 0, 0, 0}, r4 = {0, 0, 0, 0};
    float  f1 = 0.f, r1 = 0.f;
    load_rows(sino, 0, tid, f4, f1, r4, r1);
    write_rows(lds[0], tid, f4, f1, r4, r1);
    load_rows(sino, 1, tid, f4, f1, r4, r1);
    __syncthreads();

#pragma unroll 2
    for (int g = 0; g < NGRP; ++g) {
        const int buf = g & 1;
        const v2h* __restrict__ L = lds[buf];
        const v2f t = cs[g];
        // (g1, g2) = px*(c, -s) + py*(s, c)  -- packed fp32
        const v2f m1 = {t.x, -t.y};
        const v2f m2 = {t.y, t.x};
        const v2f pxv = {px, px};
        const v2f pyv = {py, py};
        const v2f gg = __builtin_elementwise_fma(pxv, m1, pyv * m2);
        const v2f cc = {UCENTER, UCENTER};
        const v2f up = cc + gg;   // (C+g1, C+g2)
        const v2f um = cc - gg;   // (C-g1, C-g2)

        visit(L, up.x, acc0, acc1);   // +g1: A->q0, B->q1
        visit(L, um.x, acc2, acc3);   // -g1: A->q2, B->q3
        visit(L, up.y, acc3, acc0);   // +g2: A->q3, B->q0
        visit(L, um.y, acc1, acc2);   // -g2: A->q1, B->q2

        if (g < NGRP - 1) {
            // lds[buf^1] last read at iter g-1, sealed by that iteration's
            // barrier -> safe to overwrite now.
            write_rows(lds[buf ^ 1], tid, f4, f1, r4, r1);
            if (g < NGRP - 2) load_rows(sino, g + 2, tid, f4, f1, r4, r1);
            __syncthreads();
        }
    }

    float* __restrict__ o = out + (size_t)b * IMGH * IMGW;
    const int hm = (IMGH - 1) - h;
    const int wm = (IMGW - 1) - w0;
    o[h  * IMGW + w0] = acc0 * DANG_F;   // q0, coalesced
    o[wm * IMGW + h ] = acc1 * DANG_F;   // q1, scattered (once)
    o[hm * IMGW + wm] = acc2 * DANG_F;   // q2, coalesced
    o[w0 * IMGW + hm] = acc3 * DANG_F;   // q3, scattered (once)
}

extern "C" void kernel_launch(void* const* d_in, const int* in_sizes, int n_in,
                              void* d_out, int out_size, void* d_ws, size_t ws_size,
                              hipStream_t stream) {
    const float* proj = (const float*)d_in[0];
    float* out = (float*)d_out;

    dim3 block(512, 1, 1);
    dim3 grid(4, 32, BATCH);   // 1024 blocks = exactly 4/CU, fully resident
    backproject_kernel<<<grid, block, 0, stream>>>(proj, out);
}

// Round 12
// 214.528 us; speedup vs baseline: 1.9894x; 1.1631x over previous
//
#include <hip/hip_runtime.h>

// CT parallel-beam pixel-driven back-projection. Static geometry.
// Fusions:
//  1) Opposing views (v, v+360) share fr (u' = 735-u): pre-summed at staging,
//     S[i] = row_v[i] + row_{v+360}[735-i] (fp32 add, one fp16 round).
//  2) View quad {v, v+180, v+360, v+540} x pixel ROTATION orbit: with
//     g1 = px*c + py*s, g2 = py*c - px*s, the 16 contributions are 4 visits
//     u = C+-g1, C+-g2; each serves pairA (v,v+360) for pixel q and pairB
//     (v+180,v+540) for the next orbit pixel.
//  3) Difference layout, 4 B entries (1-bank stride -> conflict-free):
//     entry = (D,S) fp16, D = S[i+1]-S[i]; interp = fdot2((D,S),(fr,1)).
//  4) A/B block-interleave at 64-entry granularity: A bin i at entry
//     j = i + (i & ~63), B at j + 64 -> one ds_read2_b32 per visit.
//  5) PPT=8 (two orbit reps/thread: w0 and w0+128), grid 512 = 2 blocks/CU:
//     halves per-CU staging + group overhead (they are per-BLOCK fixed
//     costs); rep1 u's derived from rep0 by +-128*(cx,-sy) packed fma.
// R9 lessons: no multi-group register prefetch (spills); entry stride 4 B.
#define BATCH 8
#define NVIEW 720
#define NPAIR 360
#define NGRP  180
#define NDET  736
#define IMGH  512
#define IMGW  512

#define DANG_F  ((float)(6.283185307179586 / 720.0))
#define RATIO_F ((float)(0.006641 / 0.0066))
#define UCENTER ((float)((NDET - 1) * 0.5))

// Entries per group-buffer: bin 735 -> j = 1439; B at +64 -> 1503.
#define LSTRIDE 1504

typedef float  v2f __attribute__((ext_vector_type(2)));
typedef __fp16 v2h __attribute__((ext_vector_type(2)));

// Staging: threads 0..183 build pairA sums (views g, g+360), 184..367 pairB
// (g+180, g+540). Thread owns bins i..i+3, needs S[i..i+4]. Overshoot
// scalars (fwd[i+4] at i=732; rev[-1]) stay inside proj (fwd rows <= 539,
// rev rows >= 360) and land only in bin 735's D, never read (i0 <= 731).
__device__ __forceinline__ void load_rows(const float* __restrict__ sino,
                                          int g, int t,
                                          float4& f4, float& f1,
                                          float4& r4, float& r1) {
    if (t < 368) {
        const int p  = (t >= 184);
        const int i  = 4 * (t - 184 * p);
        const int vf = g + 180 * p;
        const float* __restrict__ fwd = sino + vf * NDET;
        const float* __restrict__ rev = sino + (vf + NPAIR) * NDET;
        f4 = *(const float4*)(fwd + i);
        f1 = fwd[i + 4];
        r4 = *(const float4*)(rev + (732 - i));  // S-rev taps i..i+3 = (w,z,y,x)
        r1 = rev[731 - i];                       // tap i+4
    }
}

__device__ __forceinline__ void write_rows(v2h* __restrict__ L,  // [LSTRIDE]
                                           int t, float4 f4, float f1,
                                           float4 r4, float r1) {
    if (t < 368) {
        const int p = (t >= 184);
        const int i = 4 * (t - 184 * p);
        const float s0 = f4.x + r4.w;
        const float s1 = f4.y + r4.z;
        const float s2 = f4.z + r4.y;
        const float s3 = f4.w + r4.x;
        const float s4 = f1 + r1;
        const v2h n0 = __builtin_amdgcn_cvt_pkrtz(s1 - s0, s0);
        const v2h n1 = __builtin_amdgcn_cvt_pkrtz(s2 - s1, s1);
        const v2h n2 = __builtin_amdgcn_cvt_pkrtz(s3 - s2, s2);
        const v2h n3 = __builtin_amdgcn_cvt_pkrtz(s4 - s3, s3);
        // Block-interleaved index; i%64 in {0..60} -> 4 entries contiguous.
        const int j0 = i + (i & ~63) + 64 * p;
        struct alignas(16) H4 { v2h a, b, c, d; };
        *(H4*)(L + j0) = H4{n0, n1, n2, n3};     // one ds_write_b128
    }
}

// One u value: 2-view interp from pairA into accA and pairB into accB.
__device__ __forceinline__ void visit(const v2h* __restrict__ L,
                                      float u, float& accA, float& accB) {
    const int   i0 = (int)u;                      // u in [3.9, 731.1] always
    const float fr = __builtin_amdgcn_fractf(u);
    const v2h wv = __builtin_amdgcn_cvt_pkrtz(fr, 1.0f);
    const int  j  = i0 + (i0 & ~63);
    const v2h A = L[j];            // } one ds_read2_b32 offset0:0 offset1:64
    const v2h B = L[j + 64];       // }
    accA = __builtin_amdgcn_fdot2(A, wv, accA, false);   // S + fr*D
    accB = __builtin_amdgcn_fdot2(B, wv, accB, false);
}

// 512 threads = 8 waves; wave = one h row of the top-left quadrant, lanes =
// 64 consecutive w. Thread owns TWO rotation orbits: rep0 at (h, w0),
// rep1 at (h, w0+128). Grid 512 = exactly 2 blocks/CU (16 waves/CU);
// launch_bounds(512,4) allows VGPR<=128. Bounds check proven unnecessary:
// |g1|,|g2| <= 255.5*sqrt2*1.00621 = 363.6 < 367.5 -> u in [3.9, 731.1].
__global__ __launch_bounds__(512, 4) void backproject_kernel(
    const float* __restrict__ proj,  // [B, V, D]
    float* __restrict__ out)         // [B, H, W]
{
    __shared__ alignas(16) v2h lds[2][LSTRIDE];
    __shared__ v2f cs[NGRP];

    const int tid = threadIdx.x;

    if (tid < NGRP) {
        float s, c;
        sincosf((float)tid * DANG_F, &s, &c);
        cs[tid] = (v2f){c * RATIO_F, s * RATIO_F};
    }

    const int b    = blockIdx.z;
    const int lane = tid & 63;
    const int h    = (int)blockIdx.y * 8 + (tid >> 6);   // [0, 256)
    const int w0   = (int)blockIdx.x * 64 + lane;        // [0, 128)

    const float px = (float)w0 - (float)(IMGW - 1) * 0.5f;
    const float py = (float)(IMGH - 1) * 0.5f - (float)h;

    const float* __restrict__ sino = proj + (size_t)b * NVIEW * NDET;

    // Orbit accumulators. rep0: q0=(h,w0), q1=(511-w0,h), q2=(511-h,511-w0),
    // q3=(w0,511-h). rep1: same with w1 = w0+128.
    float a0 = 0.f, a1 = 0.f, a2 = 0.f, a3 = 0.f;
    float b0 = 0.f, b1 = 0.f, b2 = 0.f, b3 = 0.f;

    float4 f4 = {0, 0, 0, 0}, r4 = {0, 0, 0, 0};
    float  f1 = 0.f, r1 = 0.f;
    load_rows(sino, 0, tid, f4, f1, r4, r1);
    write_rows(lds[0], tid, f4, f1, r4, r1);
    load_rows(sino, 1, tid, f4, f1, r4, r1);
    __syncthreads();

#pragma unroll 2
    for (int g = 0; g < NGRP; ++g) {
        const int buf = g & 1;
        const v2h* __restrict__ L = lds[buf];
        const v2f t = cs[g];
        // (g1, g2) = px*(c, -s) + py*(s, c)  -- packed fp32
        const v2f m1 = {t.x, -t.y};
        const v2f m2 = {t.y, t.x};
        const v2f pxv = {px, px};
        const v2f pyv = {py, py};
        const v2f gg = __builtin_elementwise_fma(pxv, m1, pyv * m2);
        const v2f cc = {UCENTER, UCENTER};
        const v2f up = cc + gg;        // rep0 (C+g1, C+g2)
        const v2f um = cc - gg;        // rep0 (C-g1, C-g2)
        const v2f dd = {128.0f, 128.0f};
        const v2f dm = dd * m1;        // 128*(cx, -sy)
        const v2f vp = up + dm;        // rep1 (C+g1', C+g2')
        const v2f vm = um - dm;        // rep1 (C-g1', C-g2')

        visit(L, up.x, a0, a1);   // +g1: A->q0, B->q1
        visit(L, um.x, a2, a3);   // -g1: A->q2, B->q3
        visit(L, up.y, a3, a0);   // +g2: A->q3, B->q0
        visit(L, um.y, a1, a2);   // -g2: A->q1, B->q2
        visit(L, vp.x, b0, b1);
        visit(L, vm.x, b2, b3);
        visit(L, vp.y, b3, b0);
        visit(L, vm.y, b1, b2);

        if (g < NGRP - 1) {
            // lds[buf^1] last read at iter g-1, sealed by that iteration's
            // barrier -> safe to overwrite now.
            write_rows(lds[buf ^ 1], tid, f4, f1, r4, r1);
            if (g < NGRP - 2) load_rows(sino, g + 2, tid, f4, f1, r4, r1);
            __syncthreads();
        }
    }

    float* __restrict__ o = out + (size_t)b * IMGH * IMGW;
    const int hm = (IMGH - 1) - h;
    const int w1 = w0 + 128;
    const int wm0 = (IMGW - 1) - w0;
    const int wm1 = (IMGW - 1) - w1;
    o[h   * IMGW + w0 ] = a0 * DANG_F;   // coalesced
    o[wm0 * IMGW + h  ] = a1 * DANG_F;   // column write (once)
    o[hm  * IMGW + wm0] = a2 * DANG_F;   // coalesced
    o[w0  * IMGW + hm ] = a3 * DANG_F;   // column write (once)
    o[h   * IMGW + w1 ] = b0 * DANG_F;
    o[wm1 * IMGW + h  ] = b1 * DANG_F;
    o[hm  * IMGW + wm1] = b2 * DANG_F;
    o[w1  * IMGW + hm ] = b3 * DANG_F;
}

extern "C" void kernel_launch(void* const* d_in, const int* in_sizes, int n_in,
                              void* d_out, int out_size, void* d_ws, size_t ws_size,
                              hipStream_t stream) {
    const float* proj = (const float*)d_in[0];
    float* out = (float*)d_out;

    dim3 block(512, 1, 1);
    dim3 grid(2, 32, BATCH);   // 512 blocks = exactly 2/CU
    backproject_kernel<<<grid, block, 0, stream>>>(proj, out);
}

// Round 13
// 203.376 us; speedup vs baseline: 2.0985x; 1.0548x over previous
//
#include <hip/hip_runtime.h>

// CT parallel-beam pixel-driven back-projection. Static geometry.
// Fusions:
//  1) Opposing views (v, v+360) share fr (u' = 735-u): pre-summed at staging,
//     S[i] = row_v[i] + row_{v+360}[735-i] (fp32 add, one fp16 round).
//  2) View quad {v, v+180, v+360, v+540} x pixel ROTATION orbit: with
//     g1 = px*c + py*s, g2 = py*c - px*s, the 16 contributions are 4 visits
//     u = C+-g1, C+-g2; each serves pairA (v,v+360) for pixel q and pairB
//     (v+180,v+540) for the next orbit pixel.
//  3) Difference layout, 4 B entries (1-bank stride, conflict-free):
//     entry = (D,S) fp16, D = S[i+1]-S[i]; interp = fdot2((D,S),(fr,1)).
//     PLAIN layout (no block-interleave): B array at +736 entries reachable
//     by ds_read_b32 imm offset 2944. R10 lesson: ds_read2 = 2 internal LDS
//     accesses, so merging reads saves nothing; the interleave index math
//     (and+add) was pure VALU overhead.
//  4) PPT=8 (two orbit reps/thread: w0, w0+128), grid 512 = 2 blocks/CU.
//  5) TWO groups staged per barrier (90 barriers): two staging register
//     sets (~20 VGPR) — safe at launch_bounds(512,4) 128-VGPR cap (R9's
//     spill was the (512,8) 64-cap).
#define BATCH 8
#define NVIEW 720
#define NPAIR 360
#define NGRP  180
#define NDET  736
#define IMGH  512
#define IMGW  512

#define DANG_F  ((float)(6.283185307179586 / 720.0))
#define RATIO_F ((float)(0.006641 / 0.0066))
#define UCENTER ((float)((NDET - 1) * 0.5))

typedef float  v2f __attribute__((ext_vector_type(2)));
typedef __fp16 v2h __attribute__((ext_vector_type(2)));

struct Stage { float4 f4, r4; float f1, r1; };

// Staging: threads 0..183 build pairA sums (views k, k+360), 184..367 pairB
// (k+180, k+540). Thread owns bins i..i+3, needs S[i..i+4]. Overshoot
// scalars (fwd[i+4] at i=732; rev[-1]) stay inside proj (fwd rows <= 359,
// rev rows >= 360) and land only in bin 735's D, never read (i0 <= 731).
__device__ __forceinline__ void load_rows(const float* __restrict__ sino,
                                          int k, int t, Stage& S) {
    if (t < 368) {
        const int p  = (t >= 184);
        const int i  = 4 * (t - 184 * p);
        const int vf = k + 180 * p;
        const float* __restrict__ fwd = sino + vf * NDET;
        const float* __restrict__ rev = sino + (vf + NPAIR) * NDET;
        S.f4 = *(const float4*)(fwd + i);
        S.f1 = fwd[i + 4];
        S.r4 = *(const float4*)(rev + (732 - i));  // S-rev taps i..i+3=(w,z,y,x)
        S.r1 = rev[731 - i];                       // tap i+4
    }
}

__device__ __forceinline__ void write_rows(v2h* __restrict__ L,  // [2*NDET]
                                           int t, const Stage& S) {
    if (t < 368) {
        const int p = (t >= 184);
        const int i = 4 * (t - 184 * p);
        const float s0 = S.f4.x + S.r4.w;
        const float s1 = S.f4.y + S.r4.z;
        const float s2 = S.f4.z + S.r4.y;
        const float s3 = S.f4.w + S.r4.x;
        const float s4 = S.f1 + S.r1;
        const v2h n0 = __builtin_amdgcn_cvt_pkrtz(s1 - s0, s0);
        const v2h n1 = __builtin_amdgcn_cvt_pkrtz(s2 - s1, s1);
        const v2h n2 = __builtin_amdgcn_cvt_pkrtz(s3 - s2, s2);
        const v2h n3 = __builtin_amdgcn_cvt_pkrtz(s4 - s3, s3);
        struct alignas(16) H4 { v2h a, b, c, d; };
        *(H4*)(L + p * NDET + i) = H4{n0, n1, n2, n3};   // one ds_write_b128
    }
}

// One u value: 2-view interp from pairA into accA and pairB into accB.
// cvt, fract, pkrtz + addr + 2 ds_read_b32 (imm 0 / 2944) + 2 fdot2.
__device__ __forceinline__ void visit(const v2h* __restrict__ L,
                                      float u, float& accA, float& accB) {
    const int   i0 = (int)u;                      // u in [3.9, 731.1] always
    const float fr = __builtin_amdgcn_fractf(u);
    const v2h wv = __builtin_amdgcn_cvt_pkrtz(fr, 1.0f);
    const v2h A = L[i0];           // ds_read_b32
    const v2h B = L[i0 + NDET];    // ds_read_b32 offset:2944
    accA = __builtin_amdgcn_fdot2(A, wv, accA, false);   // S + fr*D
    accB = __builtin_amdgcn_fdot2(B, wv, accB, false);
}

// 512 threads = 8 waves; wave = one h row of the top-left quadrant, lanes =
// 64 consecutive w. Thread owns TWO rotation orbits: (h, w0) and (h, w0+128).
// Grid 512 = exactly 2 blocks/CU. Bounds check proven unnecessary:
// |g1|,|g2| <= 255.5*sqrt2*1.00621 = 363.6 < 367.5 -> u in [3.9, 731.1].
__global__ __launch_bounds__(512, 4) void backproject_kernel(
    const float* __restrict__ proj,  // [B, V, D]
    float* __restrict__ out)         // [B, H, W]
{
    __shared__ alignas(16) v2h lds[2][2][2 * NDET];  // [dbuf][sub][pairA|pairB]
    __shared__ v2f cs[NGRP];

    const int tid = threadIdx.x;

    if (tid < NGRP) {
        float s, c;
        sincosf((float)tid * DANG_F, &s, &c);
        cs[tid] = (v2f){c * RATIO_F, s * RATIO_F};
    }

    const int b    = blockIdx.z;
    const int lane = tid & 63;
    const int h    = (int)blockIdx.y * 8 + (tid >> 6);   // [0, 256)
    const int w0   = (int)blockIdx.x * 64 + lane;        // [0, 128)

    const float px = (float)w0 - (float)(IMGW - 1) * 0.5f;
    const float py = (float)(IMGH - 1) * 0.5f - (float)h;

    const float* __restrict__ sino = proj + (size_t)b * NVIEW * NDET;

    // Orbit accumulators. rep0: q0=(h,w0), q1=(511-w0,h), q2=(511-h,511-w0),
    // q3=(w0,511-h). rep1: same with w1 = w0+128.
    float a0 = 0.f, a1 = 0.f, a2 = 0.f, a3 = 0.f;
    float b0 = 0.f, b1 = 0.f, b2 = 0.f, b3 = 0.f;

    Stage s0 = {}, s1 = {};
    load_rows(sino, 0, tid, s0);
    load_rows(sino, 1, tid, s1);
    write_rows(lds[0][0], tid, s0);
    write_rows(lds[0][1], tid, s1);
    load_rows(sino, 2, tid, s0);
    load_rows(sino, 3, tid, s1);
    __syncthreads();

    for (int gg = 0; gg < NGRP; gg += 2) {
        const int buf = (gg >> 1) & 1;
#pragma unroll
        for (int sub = 0; sub < 2; ++sub) {
            const v2h* __restrict__ L = lds[buf][sub];
            const v2f t = cs[gg + sub];
            // (g1, g2) = px*(c, -s) + py*(s, c)  -- packed fp32
            const v2f m1 = {t.x, -t.y};
            const v2f m2 = {t.y, t.x};
            const v2f pxv = {px, px};
            const v2f pyv = {py, py};
            const v2f gvec = __builtin_elementwise_fma(pxv, m1, pyv * m2);
            const v2f cc = {UCENTER, UCENTER};
            const v2f up = cc + gvec;      // rep0 (C+g1, C+g2)
            const v2f um = cc - gvec;      // rep0 (C-g1, C-g2)
            const v2f dd = {128.0f, 128.0f};
            const v2f dm = dd * m1;        // 128*(cx, -sy)
            const v2f vp = up + dm;        // rep1
            const v2f vm = um - dm;        // rep1

            visit(L, up.x, a0, a1);   // +g1: A->q0, B->q1
            visit(L, um.x, a2, a3);   // -g1: A->q2, B->q3
            visit(L, up.y, a3, a0);   // +g2: A->q3, B->q0
            visit(L, um.y, a1, a2);   // -g2: A->q1, B->q2
            visit(L, vp.x, b0, b1);
            visit(L, vm.x, b2, b3);
            visit(L, vp.y, b3, b0);
            visit(L, vm.y, b1, b2);
        }

        if (gg < NGRP - 2) {
            // lds[buf^1] last read in the previous iteration, sealed by its
            // barrier -> safe to overwrite now.
            write_rows(lds[buf ^ 1][0], tid, s0);
            write_rows(lds[buf ^ 1][1], tid, s1);
            if (gg < NGRP - 4) {
                load_rows(sino, gg + 4, tid, s0);
                load_rows(sino, gg + 5, tid, s1);
            }
            __syncthreads();
        }
    }

    float* __restrict__ o = out + (size_t)b * IMGH * IMGW;
    const int hm  = (IMGH - 1) - h;
    const int w1  = w0 + 128;
    const int wm0 = (IMGW - 1) - w0;
    const int wm1 = (IMGW - 1) - w1;
    o[h   * IMGW + w0 ] = a0 * DANG_F;   // coalesced
    o[wm0 * IMGW + h  ] = a1 * DANG_F;   // column write (once)
    o[hm  * IMGW + wm0] = a2 * DANG_F;   // coalesced
    o[w0  * IMGW + hm ] = a3 * DANG_F;   // column write (once)
    o[h   * IMGW + w1 ] = b0 * DANG_F;
    o[wm1 * IMGW + h  ] = b1 * DANG_F;
    o[hm  * IMGW + wm1] = b2 * DANG_F;
    o[w1  * IMGW + hm ] = b3 * DANG_F;
}

extern "C" void kernel_launch(void* const* d_in, const int* in_sizes, int n_in,
                              void* d_out, int out_size, void* d_ws, size_t ws_size,
                              hipStream_t stream) {
    const float* proj = (const float*)d_in[0];
    float* out = (float*)d_out;

    dim3 block(512, 1, 1);
    dim3 grid(2, 32, BATCH);   // 512 blocks = exactly 2/CU
    backproject_kernel<<<grid, block, 0, stream>>>(proj, out);
}

// Round 15
// 177.524 us; speedup vs baseline: 2.4041x; 1.1456x over previous
//
#include <hip/hip_runtime.h>

// CT parallel-beam pixel-driven back-projection. Static geometry.
// Two-kernel design:
//   prep_kernel: precompute fused opposing-view pair arrays into d_ws —
//     pairA_g = views (g, g+360), pairB_g = (g+180, g+540), entry
//     (D,S) fp16 with S[i] = fwd[i] + rev[735-i], D = S[i+1]-S[i].
//     Pixel-independent; R12 recomputed them in every block, 90x each.
//   backproject_dma_kernel: staging = pure global_load_lds DMA (16 B width,
//     the m97-verified variant) into a 4-deep LDS ring, synced by
//     __syncthreads (compiler-inserted vmcnt drain — R13's hand-encoded
//     s_waitcnt produced NaN; never bet on unverified encodings).
// Symmetries (verified R7-R12): view quad {v,v+180,v+360,v+540} x pixel
// rotation orbit; 4 visits u = C+-g1, C+-g2 per group serve 16 pixel-views.
// Fallback: if ws_size < needed, launch the proven R12 kernel (161 us).
#define BATCH 8
#define NVIEW 720
#define NPAIR 360
#define NGRP  180
#define NDET  736
#define IMGH  512
#define IMGW  512

#define DANG_F  ((float)(6.283185307179586 / 720.0))
#define RATIO_F ((float)(0.006641 / 0.0066))
#define UCENTER ((float)((NDET - 1) * 0.5))

#define PADDET 768   // padded entries per pair-array (1024B DMA slice tiling)
#define ITER_BYTES 12288  // 4 arrays x 768 entries x 4 B per iteration
#define WS_BYTES ((size_t)BATCH * NGRP * 2 * PADDET * 4)

typedef float  v2f __attribute__((ext_vector_type(2)));
typedef __fp16 v2h __attribute__((ext_vector_type(2)));

// ---------------- prep kernel ----------------
// grid (3, 360, 8), block 256. y = g*2+pair; fwd row = g+180*pair,
// rev row = fwd+360 (<720). Entry i<736; pad [736,768) left unwritten
// (never read: i0 <= 731).
__global__ __launch_bounds__(256) void prep_kernel(
    const float* __restrict__ proj, v2h* __restrict__ ws)
{
    const int i = blockIdx.x * 256 + threadIdx.x;
    if (i >= NDET) return;
    const int y = blockIdx.y;
    const int b = blockIdx.z;
    const int g    = y >> 1;
    const int pair = y & 1;
    const int frow = g + 180 * pair;
    const float* __restrict__ fwd = proj + ((size_t)b * NVIEW + frow) * NDET;
    const float* __restrict__ rev = fwd + (size_t)NPAIR * NDET;
    const int i1 = (i < NDET - 1) ? i + 1 : i;     // D=0 at i=735 (unread)
    const float s0 = fwd[i]  + rev[735 - i];
    const float s1 = fwd[i1] + rev[735 - i1];
    ws[((size_t)b * NGRP * 2 + y) * PADDET + i] =
        __builtin_amdgcn_cvt_pkrtz(s1 - s0, s0);   // (D, S)
}

// One u value: 2-view interp from pairA into accA and pairB into accB.
__device__ __forceinline__ void visit(const v2h* __restrict__ L,
                                      float u, float& accA, float& accB) {
    const int   i0 = (int)u;                      // u in [3.9, 731.1] always
    const float fr = __builtin_amdgcn_fractf(u);
    const v2h wv = __builtin_amdgcn_cvt_pkrtz(fr, 1.0f);
    const v2h A = L[i0];              // ds_read_b32
    const v2h B = L[i0 + PADDET];     // ds_read_b32 offset:3072
    accA = __builtin_amdgcn_fdot2(A, wv, accA, false);   // S + fr*D
    accB = __builtin_amdgcn_fdot2(B, wv, accB, false);
}

// ---------------- main kernel (DMA path) ----------------
// 512 threads = 8 waves; wave = one h row of the top-left quadrant, lanes =
// 64 consecutive w; thread owns two rotation orbits (w0, w0+128).
// Grid 512 = exactly 2 blocks/CU. Iteration p stages groups (2p, 2p+1):
// 12288 B = 12 slices of 1024 B (64 lanes x 16 B); wave w takes slice w,
// waves 0..3 also take slice 8+w (wave-uniform branch).
// Ring-safety (4-deep): issue(p+1) -> slot (p+1)&3; concurrent readers
// between barrier(p-1) and barrier(p) touch slots (p-1)&3 (groups(p-1))
// and p&3 (groups(p), after barrier) — both differ from (p+1)&3 mod 4.
// Prior content of slot (p+1)&3 was iter p-3, last read in groups(p-3)
// before barrier(p-2) < barrier(p-1), which the issuing wave has passed.
// Bounds check proven unnecessary: |g1|,|g2| <= 363.6 < 367.5.
__global__ __launch_bounds__(512, 4) void backproject_dma_kernel(
    const v2h* __restrict__ ws, float* __restrict__ out)
{
    __shared__ alignas(16) v2h lds4[4][2 * 2 * PADDET];  // 4 x 12288 B ring
    __shared__ v2f cs[NGRP];

    const int tid  = threadIdx.x;
    const int wave = tid >> 6;
    const int lane = tid & 63;

    if (tid < NGRP) {
        float s, c;
        sincosf((float)tid * DANG_F, &s, &c);
        cs[tid] = (v2f){c * RATIO_F, s * RATIO_F};   // sealed by 1st barrier
    }

    const int b  = blockIdx.z;
    const int h  = (int)blockIdx.y * 8 + wave;           // [0, 256)
    const int w0 = (int)blockIdx.x * 64 + lane;          // [0, 128)

    const float px = (float)w0 - (float)(IMGW - 1) * 0.5f;
    const float py = (float)(IMGH - 1) * 0.5f - (float)h;

    const char* __restrict__ wsb =
        (const char*)(ws + (size_t)b * NGRP * 2 * PADDET);

    float a0 = 0.f, a1 = 0.f, a2 = 0.f, a3 = 0.f;
    float b0 = 0.f, b1 = 0.f, b2 = 0.f, b3 = 0.f;

    auto issue = [&](int p) {
        const char* g0 = wsb + (size_t)p * ITER_BYTES;
        char* l0 = (char*)&lds4[p & 3][0];
        __builtin_amdgcn_global_load_lds(
            (const __attribute__((address_space(1))) void*)
                (g0 + wave * 1024 + lane * 16),
            (__attribute__((address_space(3))) void*)(l0 + wave * 1024),
            16, 0, 0);
        if (wave < 4) {
            const int s = 8 + wave;
            __builtin_amdgcn_global_load_lds(
                (const __attribute__((address_space(1))) void*)
                    (g0 + s * 1024 + lane * 16),
                (__attribute__((address_space(3))) void*)(l0 + s * 1024),
                16, 0, 0);
        }
    };

    auto groups = [&](int p) {
        const v2h* __restrict__ L4 = &lds4[p & 3][0];
#pragma unroll
        for (int sub = 0; sub < 2; ++sub) {
            const v2h* __restrict__ L = L4 + sub * (2 * PADDET);
            const v2f t = cs[2 * p + sub];
            // (g1, g2) = px*(c, -s) + py*(s, c)  -- packed fp32
            const v2f m1 = {t.x, -t.y};
            const v2f m2 = {t.y, t.x};
            const v2f pxv = {px, px};
            const v2f pyv = {py, py};
            const v2f gvec = __builtin_elementwise_fma(pxv, m1, pyv * m2);
            const v2f cc = {UCENTER, UCENTER};
            const v2f up = cc + gvec;      // rep0 (C+g1, C+g2)
            const v2f um = cc - gvec;      // rep0 (C-g1, C-g2)
            const v2f dd = {128.0f, 128.0f};
            const v2f dm = dd * m1;        // 128*(cx, -sy)
            const v2f vp = up + dm;        // rep1
            const v2f vm = um - dm;        // rep1

            visit(L, up.x, a0, a1);   // +g1: A->q0, B->q1
            visit(L, um.x, a2, a3);   // -g1: A->q2, B->q3
            visit(L, up.y, a3, a0);   // +g2: A->q3, B->q0
            visit(L, um.y, a1, a2);   // -g2: A->q1, B->q2
            visit(L, vp.x, b0, b1);
            visit(L, vm.x, b2, b3);
            visit(L, vp.y, b3, b0);
            visit(L, vm.y, b1, b2);
        }
    };

    issue(0);
    for (int p = 0; p < 90; ++p) {
        if (p + 1 < 90) issue(p + 1);
        __syncthreads();    // drains vmcnt: slots p (and p+1) fully landed
        groups(p);
    }

    float* __restrict__ o = out + (size_t)b * IMGH * IMGW;
    const int hm  = (IMGH - 1) - h;
    const int w1  = w0 + 128;
    const int wm0 = (IMGW - 1) - w0;
    const int wm1 = (IMGW - 1) - w1;
    o[h   * IMGW + w0 ] = a0 * DANG_F;
    o[wm0 * IMGW + h  ] = a1 * DANG_F;
    o[hm  * IMGW + wm0] = a2 * DANG_F;
    o[w0  * IMGW + hm ] = a3 * DANG_F;
    o[h   * IMGW + w1 ] = b0 * DANG_F;
    o[wm1 * IMGW + h  ] = b1 * DANG_F;
    o[hm  * IMGW + wm1] = b2 * DANG_F;
    o[w1  * IMGW + hm ] = b3 * DANG_F;
}

// ---------------- fallback (R12, proven 161 us) ----------------
struct Stage { float4 f4, r4; float f1, r1; };

__device__ __forceinline__ void fb_load(const float* __restrict__ sino,
                                        int k, int t, Stage& S) {
    if (t < 368) {
        const int p  = (t >= 184);
        const int i  = 4 * (t - 184 * p);
        const int vf = k + 180 * p;
        const float* __restrict__ fwd = sino + vf * NDET;
        const float* __restrict__ rev = sino + (vf + NPAIR) * NDET;
        S.f4 = *(const float4*)(fwd + i);
        S.f1 = fwd[i + 4];
        S.r4 = *(const float4*)(rev + (732 - i));
        S.r1 = rev[731 - i];
    }
}

__device__ __forceinline__ void fb_write(v2h* __restrict__ L, int t,
                                         const Stage& S) {
    if (t < 368) {
        const int p = (t >= 184);
        const int i = 4 * (t - 184 * p);
        const float s0 = S.f4.x + S.r4.w;
        const float s1 = S.f4.y + S.r4.z;
        const float s2 = S.f4.z + S.r4.y;
        const float s3 = S.f4.w + S.r4.x;
        const float s4 = S.f1 + S.r1;
        const v2h n0 = __builtin_amdgcn_cvt_pkrtz(s1 - s0, s0);
        const v2h n1 = __builtin_amdgcn_cvt_pkrtz(s2 - s1, s1);
        const v2h n2 = __builtin_amdgcn_cvt_pkrtz(s3 - s2, s2);
        const v2h n3 = __builtin_amdgcn_cvt_pkrtz(s4 - s3, s3);
        struct alignas(16) H4 { v2h a, b, c, d; };
        *(H4*)(L + p * NDET + i) = H4{n0, n1, n2, n3};
    }
}

__device__ __forceinline__ void fb_visit(const v2h* __restrict__ L,
                                         float u, float& accA, float& accB) {
    const int   i0 = (int)u;
    const float fr = __builtin_amdgcn_fractf(u);
    const v2h wv = __builtin_amdgcn_cvt_pkrtz(fr, 1.0f);
    const v2h A = L[i0];
    const v2h B = L[i0 + NDET];
    accA = __builtin_amdgcn_fdot2(A, wv, accA, false);
    accB = __builtin_amdgcn_fdot2(B, wv, accB, false);
}

__global__ __launch_bounds__(512, 4) void backproject_fb_kernel(
    const float* __restrict__ proj, float* __restrict__ out)
{
    __shared__ alignas(16) v2h lds[2][2][2 * NDET];
    __shared__ v2f cs[NGRP];

    const int tid = threadIdx.x;
    if (tid < NGRP) {
        float s, c;
        sincosf((float)tid * DANG_F, &s, &c);
        cs[tid] = (v2f){c * RATIO_F, s * RATIO_F};
    }

    const int b    = blockIdx.z;
    const int lane = tid & 63;
    const int h    = (int)blockIdx.y * 8 + (tid >> 6);
    const int w0   = (int)blockIdx.x * 64 + lane;

    const float px = (float)w0 - (float)(IMGW - 1) * 0.5f;
    const float py = (float)(IMGH - 1) * 0.5f - (float)h;

    const float* __restrict__ sino = proj + (size_t)b * NVIEW * NDET;

    float a0 = 0.f, a1 = 0.f, a2 = 0.f, a3 = 0.f;
    float b0 = 0.f, b1 = 0.f, b2 = 0.f, b3 = 0.f;

    Stage s0 = {}, s1 = {};
    fb_load(sino, 0, tid, s0);
    fb_load(sino, 1, tid, s1);
    fb_write(lds[0][0], tid, s0);
    fb_write(lds[0][1], tid, s1);
    fb_load(sino, 2, tid, s0);
    fb_load(sino, 3, tid, s1);
    __syncthreads();

    for (int gg = 0; gg < NGRP; gg += 2) {
        const int buf = (gg >> 1) & 1;
#pragma unroll
        for (int sub = 0; sub < 2; ++sub) {
            const v2h* __restrict__ L = lds[buf][sub];
            const v2f t = cs[gg + sub];
            const v2f m1 = {t.x, -t.y};
            const v2f m2 = {t.y, t.x};
            const v2f pxv = {px, px};
            const v2f pyv = {py, py};
            const v2f gvec = __builtin_elementwise_fma(pxv, m1, pyv * m2);
            const v2f cc = {UCENTER, UCENTER};
            const v2f up = cc + gvec;
            const v2f um = cc - gvec;
            const v2f dd = {128.0f, 128.0f};
            const v2f dm = dd * m1;
            const v2f vp = up + dm;
            const v2f vm = um - dm;

            fb_visit(L, up.x, a0, a1);
            fb_visit(L, um.x, a2, a3);
            fb_visit(L, up.y, a3, a0);
            fb_visit(L, um.y, a1, a2);
            fb_visit(L, vp.x, b0, b1);
            fb_visit(L, vm.x, b2, b3);
            fb_visit(L, vp.y, b3, b0);
            fb_visit(L, vm.y, b1, b2);
        }
        if (gg < NGRP - 2) {
            fb_write(lds[buf ^ 1][0], tid, s0);
            fb_write(lds[buf ^ 1][1], tid, s1);
            if (gg < NGRP - 4) {
                fb_load(sino, gg + 4, tid, s0);
                fb_load(sino, gg + 5, tid, s1);
            }
            __syncthreads();
        }
    }

    float* __restrict__ o = out + (size_t)b * IMGH * IMGW;
    const int hm  = (IMGH - 1) - h;
    const int w1  = w0 + 128;
    const int wm0 = (IMGW - 1) - w0;
    const int wm1 = (IMGW - 1) - w1;
    o[h   * IMGW + w0 ] = a0 * DANG_F;
    o[wm0 * IMGW + h  ] = a1 * DANG_F;
    o[hm  * IMGW + wm0] = a2 * DANG_F;
    o[w0  * IMGW + hm ] = a3 * DANG_F;
    o[h   * IMGW + w1 ] = b0 * DANG_F;
    o[wm1 * IMGW + h  ] = b1 * DANG_F;
    o[hm  * IMGW + wm1] = b2 * DANG_F;
    o[w1  * IMGW + hm ] = b3 * DANG_F;
}

extern "C" void kernel_launch(void* const* d_in, const int* in_sizes, int n_in,
                              void* d_out, int out_size, void* d_ws, size_t ws_size,
                              hipStream_t stream) {
    const float* proj = (const float*)d_in[0];
    float* out = (float*)d_out;

    if (ws_size >= WS_BYTES) {
        v2h* ws = (v2h*)d_ws;
        prep_kernel<<<dim3(3, 360, BATCH), 256, 0, stream>>>(proj, ws);
        backproject_dma_kernel<<<dim3(2, 32, BATCH), 512, 0, stream>>>(ws, out);
    } else {
        backproject_fb_kernel<<<dim3(2, 32, BATCH), 512, 0, stream>>>(proj, out);
    }
}

// Round 16
// 170.080 us; speedup vs baseline: 2.5093x; 1.0438x over previous
//
#include <hip/hip_runtime.h>

// CT parallel-beam pixel-driven back-projection. Static geometry.
// Two-kernel design:
//   prep_kernel: precompute fused opposing-view pair arrays into d_ws —
//     pairA_g = views (g, g+360), pairB_g = (g+180, g+540), entry
//     (D,S) fp16 with S[i] = fwd[i] + rev[735-i], D = S[i+1]-S[i].
//     v2: 2880 blocks x 192 threads, float4 loads / dwordx4 store (R14's
//     scalar prep cost ~40 us of the 177 total).
//   backproject_dma_kernel: staging = pure global_load_lds DMA (16 B) into
//     a 4-deep LDS ring. R15 reorder: issue(p+1) BEFORE groups(p), barrier
//     AFTER — the __syncthreads vmcnt(0) drain then waits on a DMA aged by
//     ~2800 cyc of compute (free), not a fresh one (R14 paid a full L2
//     round-trip per iteration).
// Symmetries (verified R7-R12): view quad {v,v+180,v+360,v+540} x pixel
// rotation orbit; 4 visits u = C+-g1, C+-g2 per group serve 16 pixel-views.
// Fallback: if ws_size < needed, launch the proven R12 kernel (161 us).
#define BATCH 8
#define NVIEW 720
#define NPAIR 360
#define NGRP  180
#define NDET  736
#define IMGH  512
#define IMGW  512

#define DANG_F  ((float)(6.283185307179586 / 720.0))
#define RATIO_F ((float)(0.006641 / 0.0066))
#define UCENTER ((float)((NDET - 1) * 0.5))

#define PADDET 768   // padded entries per pair-array (1024B DMA slice tiling)
#define ITER_BYTES 12288  // 4 arrays x 768 entries x 4 B per iteration
#define WS_BYTES ((size_t)BATCH * NGRP * 2 * PADDET * 4)

typedef float  v2f __attribute__((ext_vector_type(2)));
typedef __fp16 v2h __attribute__((ext_vector_type(2)));

// ---------------- prep kernel (v2: vectorized) ----------------
// grid (360, 8), block 192 (threads 0..183 active). y = g*2+pair;
// fwd row = g+180*pair (<540), rev row = fwd+360 (<900<720*8 in-batch... 
// rev = fwd + 360 rows, max 539+360 = 899 < 720? No: 539+360=899 >= 720!).
// NOTE: rev row index = frow + 360; frow <= 539 only when pair=1,g=179:
// frow = 179+180 = 359 -> rev = 719. pair=1 means frow in [180,359],
// pair=0 frow in [0,179]. So rev in [360,719]. All in-range.
// Thread owns bins i..i+3 (i=4t). Overshoot: fwd[i+4] at i=732 -> next row
// elem 0 (in proj); rev[-1] -> prev row last elem (rev>=360>=1). Both land
// only in bin 735's D, never read (i0 <= 731). Pad [736,768) unwritten,
// DMA'd but never read.
__global__ __launch_bounds__(192) void prep_kernel(
    const float* __restrict__ proj, v2h* __restrict__ ws)
{
    const int t = threadIdx.x;
    if (t >= 184) return;
    const int y = blockIdx.x;
    const int b = blockIdx.y;
    const int g    = y >> 1;
    const int pair = y & 1;
    const int frow = g + 180 * pair;
    const int i = 4 * t;
    const float* __restrict__ fwd = proj + ((size_t)b * NVIEW + frow) * NDET;
    const float* __restrict__ rev = fwd + (size_t)NPAIR * NDET;
    const float4 f4 = *(const float4*)(fwd + i);
    const float  f1 = fwd[i + 4];
    const float4 r4 = *(const float4*)(rev + (732 - i));  // taps i..i+3=(w,z,y,x)
    const float  r1 = rev[731 - i];                       // tap i+4
    const float s0 = f4.x + r4.w;
    const float s1 = f4.y + r4.z;
    const float s2 = f4.z + r4.y;
    const float s3 = f4.w + r4.x;
    const float s4 = f1 + r1;
    const v2h n0 = __builtin_amdgcn_cvt_pkrtz(s1 - s0, s0);   // (D, S)
    const v2h n1 = __builtin_amdgcn_cvt_pkrtz(s2 - s1, s1);
    const v2h n2 = __builtin_amdgcn_cvt_pkrtz(s3 - s2, s2);
    const v2h n3 = __builtin_amdgcn_cvt_pkrtz(s4 - s3, s3);
    struct alignas(16) H4 { v2h a, b, c, d; };
    *(H4*)(ws + ((size_t)b * NGRP * 2 + y) * PADDET + i) = H4{n0, n1, n2, n3};
}

// One u value: 2-view interp from pairA into accA and pairB into accB.
__device__ __forceinline__ void visit(const v2h* __restrict__ L,
                                      float u, float& accA, float& accB) {
    const int   i0 = (int)u;                      // u in [3.9, 731.1] always
    const float fr = __builtin_amdgcn_fractf(u);
    const v2h wv = __builtin_amdgcn_cvt_pkrtz(fr, 1.0f);
    const v2h A = L[i0];              // ds_read_b32
    const v2h B = L[i0 + PADDET];     // ds_read_b32 offset:3072
    accA = __builtin_amdgcn_fdot2(A, wv, accA, false);   // S + fr*D
    accB = __builtin_amdgcn_fdot2(B, wv, accB, false);
}

// ---------------- main kernel (DMA path) ----------------
// 512 threads = 8 waves; wave = one h row of the top-left quadrant, lanes =
// 64 consecutive w; thread owns two rotation orbits (w0, w0+128).
// Grid 512 = exactly 2 blocks/CU. Iteration p stages groups (2p, 2p+1):
// 12288 B = 12 slices of 1024 B (64 lanes x 16 B); wave w takes slice w,
// waves 0..3 also take slice 8+w (wave-uniform branch).
// Pipeline (R15): issue(p+1) -> groups(p) -> __syncthreads. The barrier's
// vmcnt(0) drain waits on a DMA aged by groups(p) (~2800 cyc) -> free.
// groups(p)'s slot p&3 was drained by iteration p-1's end barrier.
// Ring safety: issue(p+1) writes slot (p+1)&3 while groups(p) reads p&3;
// prior content of slot (p+1)&3 (iter p-3) was last read in groups(p-3),
// sealed by that iteration's end barrier, which all waves have passed.
// Bounds check proven unnecessary: |g1|,|g2| <= 363.6 < 367.5.
__global__ __launch_bounds__(512, 4) void backproject_dma_kernel(
    const v2h* __restrict__ ws, float* __restrict__ out)
{
    __shared__ alignas(16) v2h lds4[4][2 * 2 * PADDET];  // 4 x 12288 B ring
    __shared__ v2f cs[NGRP];

    const int tid  = threadIdx.x;
    const int wave = tid >> 6;
    const int lane = tid & 63;

    if (tid < NGRP) {
        float s, c;
        sincosf((float)tid * DANG_F, &s, &c);
        cs[tid] = (v2f){c * RATIO_F, s * RATIO_F};   // sealed by 1st barrier
    }

    const int b  = blockIdx.z;
    const int h  = (int)blockIdx.y * 8 + wave;           // [0, 256)
    const int w0 = (int)blockIdx.x * 64 + lane;          // [0, 128)

    const float px = (float)w0 - (float)(IMGW - 1) * 0.5f;
    const float py = (float)(IMGH - 1) * 0.5f - (float)h;

    const char* __restrict__ wsb =
        (const char*)(ws + (size_t)b * NGRP * 2 * PADDET);

    float a0 = 0.f, a1 = 0.f, a2 = 0.f, a3 = 0.f;
    float b0 = 0.f, b1 = 0.f, b2 = 0.f, b3 = 0.f;

    auto issue = [&](int p) {
        const char* g0 = wsb + (size_t)p * ITER_BYTES;
        char* l0 = (char*)&lds4[p & 3][0];
        __builtin_amdgcn_global_load_lds(
            (const __attribute__((address_space(1))) void*)
                (g0 + wave * 1024 + lane * 16),
            (__attribute__((address_space(3))) void*)(l0 + wave * 1024),
            16, 0, 0);
        if (wave < 4) {
            const int s = 8 + wave;
            __builtin_amdgcn_global_load_lds(
                (const __attribute__((address_space(1))) void*)
                    (g0 + s * 1024 + lane * 16),
                (__attribute__((address_space(3))) void*)(l0 + s * 1024),
                16, 0, 0);
        }
    };

    auto groups = [&](int p) {
        const v2h* __restrict__ L4 = &lds4[p & 3][0];
#pragma unroll
        for (int sub = 0; sub < 2; ++sub) {
            const v2h* __restrict__ L = L4 + sub * (2 * PADDET);
            const v2f t = cs[2 * p + sub];
            // (g1, g2) = px*(c, -s) + py*(s, c)  -- packed fp32
            const v2f m1 = {t.x, -t.y};
            const v2f m2 = {t.y, t.x};
            const v2f pxv = {px, px};
            const v2f pyv = {py, py};
            const v2f gvec = __builtin_elementwise_fma(pxv, m1, pyv * m2);
            const v2f cc = {UCENTER, UCENTER};
            const v2f up = cc + gvec;      // rep0 (C+g1, C+g2)
            const v2f um = cc - gvec;      // rep0 (C-g1, C-g2)
            const v2f dd = {128.0f, 128.0f};
            const v2f dm = dd * m1;        // 128*(cx, -sy)
            const v2f vp = up + dm;        // rep1
            const v2f vm = um - dm;        // rep1

            visit(L, up.x, a0, a1);   // +g1: A->q0, B->q1
            visit(L, um.x, a2, a3);   // -g1: A->q2, B->q3
            visit(L, up.y, a3, a0);   // +g2: A->q3, B->q0
            visit(L, um.y, a1, a2);   // -g2: A->q1, B->q2
            visit(L, vp.x, b0, b1);
            visit(L, vm.x, b2, b3);
            visit(L, vp.y, b3, b0);
            visit(L, vm.y, b1, b2);
        }
    };

    issue(0);
    __syncthreads();   // drains issue(0) (once) + seals cs[]
    for (int p = 0; p < 90; ++p) {
        if (p + 1 < 90) issue(p + 1);
        groups(p);
        if (p + 1 < 90) __syncthreads();   // drain aged DMA; RW separation
    }

    float* __restrict__ o = out + (size_t)b * IMGH * IMGW;
    const int hm  = (IMGH - 1) - h;
    const int w1  = w0 + 128;
    const int wm0 = (IMGW - 1) - w0;
    const int wm1 = (IMGW - 1) - w1;
    o[h   * IMGW + w0 ] = a0 * DANG_F;
    o[wm0 * IMGW + h  ] = a1 * DANG_F;
    o[hm  * IMGW + wm0] = a2 * DANG_F;
    o[w0  * IMGW + hm ] = a3 * DANG_F;
    o[h   * IMGW + w1 ] = b0 * DANG_F;
    o[wm1 * IMGW + h  ] = b1 * DANG_F;
    o[hm  * IMGW + wm1] = b2 * DANG_F;
    o[w1  * IMGW + hm ] = b3 * DANG_F;
}

// ---------------- fallback (R12, proven 161 us) ----------------
struct Stage { float4 f4, r4; float f1, r1; };

__device__ __forceinline__ void fb_load(const float* __restrict__ sino,
                                        int k, int t, Stage& S) {
    if (t < 368) {
        const int p  = (t >= 184);
        const int i  = 4 * (t - 184 * p);
        const int vf = k + 180 * p;
        const float* __restrict__ fwd = sino + vf * NDET;
        const float* __restrict__ rev = sino + (vf + NPAIR) * NDET;
        S.f4 = *(const float4*)(fwd + i);
        S.f1 = fwd[i + 4];
        S.r4 = *(const float4*)(rev + (732 - i));
        S.r1 = rev[731 - i];
    }
}

__device__ __forceinline__ void fb_write(v2h* __restrict__ L, int t,
                                         const Stage& S) {
    if (t < 368) {
        const int p = (t >= 184);
        const int i = 4 * (t - 184 * p);
        const float s0 = S.f4.x + S.r4.w;
        const float s1 = S.f4.y + S.r4.z;
        const float s2 = S.f4.z + S.r4.y;
        const float s3 = S.f4.w + S.r4.x;
        const float s4 = S.f1 + S.r1;
        const v2h n0 = __builtin_amdgcn_cvt_pkrtz(s1 - s0, s0);
        const v2h n1 = __builtin_amdgcn_cvt_pkrtz(s2 - s1, s1);
        const v2h n2 = __builtin_amdgcn_cvt_pkrtz(s3 - s2, s2);
        const v2h n3 = __builtin_amdgcn_cvt_pkrtz(s4 - s3, s3);
        struct alignas(16) H4 { v2h a, b, c, d; };
        *(H4*)(L + p * NDET + i) = H4{n0, n1, n2, n3};
    }
}

__device__ __forceinline__ void fb_visit(const v2h* __restrict__ L,
                                         float u, float& accA, float& accB) {
    const int   i0 = (int)u;
    const float fr = __builtin_amdgcn_fractf(u);
    const v2h wv = __builtin_amdgcn_cvt_pkrtz(fr, 1.0f);
    const v2h A = L[i0];
    const v2h B = L[i0 + NDET];
    accA = __builtin_amdgcn_fdot2(A, wv, accA, false);
    accB = __builtin_amdgcn_fdot2(B, wv, accB, false);
}

__global__ __launch_bounds__(512, 4) void backproject_fb_kernel(
    const float* __restrict__ proj, float* __restrict__ out)
{
    __shared__ alignas(16) v2h lds[2][2][2 * NDET];
    __shared__ v2f cs[NGRP];

    const int tid = threadIdx.x;
    if (tid < NGRP) {
        float s, c;
        sincosf((float)tid * DANG_F, &s, &c);
        cs[tid] = (v2f){c * RATIO_F, s * RATIO_F};
    }

    const int b    = blockIdx.z;
    const int lane = tid & 63;
    const int h    = (int)blockIdx.y * 8 + (tid >> 6);
    const int w0   = (int)blockIdx.x * 64 + lane;

    const float px = (float)w0 - (float)(IMGW - 1) * 0.5f;
    const float py = (float)(IMGH - 1) * 0.5f - (float)h;

    const float* __restrict__ sino = proj + (size_t)b * NVIEW * NDET;

    float a0 = 0.f, a1 = 0.f, a2 = 0.f, a3 = 0.f;
    float b0 = 0.f, b1 = 0.f, b2 = 0.f, b3 = 0.f;

    Stage s0 = {}, s1 = {};
    fb_load(sino, 0, tid, s0);
    fb_load(sino, 1, tid, s1);
    fb_write(lds[0][0], tid, s0);
    fb_write(lds[0][1], tid, s1);
    fb_load(sino, 2, tid, s0);
    fb_load(sino, 3, tid, s1);
    __syncthreads();

    for (int gg = 0; gg < NGRP; gg += 2) {
        const int buf = (gg >> 1) & 1;
#pragma unroll
        for (int sub = 0; sub < 2; ++sub) {
            const v2h* __restrict__ L = lds[buf][sub];
            const v2f t = cs[gg + sub];
            const v2f m1 = {t.x, -t.y};
            const v2f m2 = {t.y, t.x};
            const v2f pxv = {px, px};
            const v2f pyv = {py, py};
            const v2f gvec = __builtin_elementwise_fma(pxv, m1, pyv * m2);
            const v2f cc = {UCENTER, UCENTER};
            const v2f up = cc + gvec;
            const v2f um = cc - gvec;
            const v2f dd = {128.0f, 128.0f};
            const v2f dm = dd * m1;
            const v2f vp = up + dm;
            const v2f vm = um - dm;

            fb_visit(L, up.x, a0, a1);
            fb_visit(L, um.x, a2, a3);
            fb_visit(L, up.y, a3, a0);
            fb_visit(L, um.y, a1, a2);
            fb_visit(L, vp.x, b0, b1);
            fb_visit(L, vm.x, b2, b3);
            fb_visit(L, vp.y, b3, b0);
            fb_visit(L, vm.y, b1, b2);
        }
        if (gg < NGRP - 2) {
            fb_write(lds[buf ^ 1][0], tid, s0);
            fb_write(lds[buf ^ 1][1], tid, s1);
            if (gg < NGRP - 4) {
                fb_load(sino, gg + 4, tid, s0);
                fb_load(sino, gg + 5, tid, s1);
            }
            __syncthreads();
        }
    }

    float* __restrict__ o = out + (size_t)b * IMGH * IMGW;
    const int hm  = (IMGH - 1) - h;
    const int w1  = w0 + 128;
    const int wm0 = (IMGW - 1) - w0;
    const int wm1 = (IMGW - 1) - w1;
    o[h   * IMGW + w0 ] = a0 * DANG_F;
    o[wm0 * IMGW + h  ] = a1 * DANG_F;
    o[hm  * IMGW + wm0] = a2 * DANG_F;
    o[w0  * IMGW + hm ] = a3 * DANG_F;
    o[h   * IMGW + w1 ] = b0 * DANG_F;
    o[wm1 * IMGW + h  ] = b1 * DANG_F;
    o[hm  * IMGW + wm1] = b2 * DANG_F;
    o[w1  * IMGW + hm ] = b3 * DANG_F;
}

extern "C" void kernel_launch(void* const* d_in, const int* in_sizes, int n_in,
                              void* d_out, int out_size, void* d_ws, size_t ws_size,
                              hipStream_t stream) {
    const float* proj = (const float*)d_in[0];
    float* out = (float*)d_out;

    if (ws_size >= WS_BYTES) {
        v2h* ws = (v2h*)d_ws;
        prep_kernel<<<dim3(360, BATCH), 192, 0, stream>>>(proj, ws);
        backproject_dma_kernel<<<dim3(2, 32, BATCH), 512, 0, stream>>>(ws, out);
    } else {
        backproject_fb_kernel<<<dim3(2, 32, BATCH), 512, 0, stream>>>(proj, out);
    }
}